// Round 6
// baseline (331.074 us; speedup 1.0000x reference)
//
#include <hip/hip_runtime.h>
#include <math.h>

#define BB 8
#define HH 512
#define WW 1024
#define HW (HH * WW)          // 524288 = 2^19
#define NPIX (BB * HW)        // 4194304
#define NSEG 16               // segments 1..16 (0 skipped)
#define SUPPRESS 0.1f

// ws layout (bytes):
//   moments4 : double[4][8][16][14] @ 0      (57344)   4-way spread partials
//   res4     : double[4][8][16]     @ 57344  (4096)
//   scal64   : double[64][4]        @ 61440  (2048)    [dx,dy,Sb,Sbf] partials
//   maxfg64  : unsigned[64]         @ 63488  (256)
//   params   : float[128*6]         @ 63744  (3072)
//   valid    : int[128]             @ 66816  (512)

// ---------------- K_M: row-decomposed segment moments ----------------
// Each wave owns ONE image row (y constant) and one feature group:
//   GRP 0: N, Sx, Sxx, Su   (+ derived Sy=yN, Sxy=ySx, Syy=y^2 N, Syu=ySu)
//   GRP 1: Sv, Suu, Svv, Sxu, Sxv (+ derived Syv=ySv)
// Register accumulators only (r5's VGPR_Count=64 proved acc spilled; here
// launch_bounds(256,2) caps VGPR at 256 -> spill-free at ~120 regs).
// moment index order: [n,Sx,Sy,Sxx,Sxy,Syy,Su,Sv,Suu,Svv,Sxu,Syu,Sxv,Syv]
template <int GRP>
__device__ __forceinline__ void mom_body(
    const float* __restrict__ fuR, const float* __restrict__ fvR,
    const int*   __restrict__ mkR, const int lane,
    double* __restrict__ cell, const double yd)
{
    constexpr int NK = (GRP == 0) ? 4 : 5;
    float acc[NK][16];
    #pragma unroll
    for (int k = 0; k < NK; ++k)
        #pragma unroll
        for (int s = 0; s < 16; ++s) acc[k][s] = 0.f;

    const int o0 = lane * 4;
    int4   m4 = *(const int4*)&mkR[o0];
    float4 u4 = *(const float4*)&fuR[o0];
    float4 v4 = *(const float4*)&fvR[o0];

    #pragma unroll 1
    for (int it = 0; it < 4; ++it) {
        // prefetch next iteration (wraps to 0 on last iter; harmless L1 hit)
        const int on = ((it + 1) & 3) * 256 + lane * 4;
        const int4   m4n = *(const int4*)&mkR[on];
        const float4 u4n = *(const float4*)&fuR[on];
        const float4 v4n = *(const float4*)&fvR[on];

        const float xb = (float)(it * 256 + lane * 4);
        const int   segs[4] = {m4.x, m4.y, m4.z, m4.w};
        const float us[4]   = {u4.x, u4.y, u4.z, u4.w};
        const float ws[4]   = {v4.x, v4.y, v4.z, v4.w};
        #pragma unroll
        for (int j = 0; j < 4; ++j) {
            const int   seg = segs[j];
            const float x = xb + (float)j;
            const float u = us[j], v = ws[j];
            float f0, f1, f2, f3, f4;
            if constexpr (GRP == 0) {
                f0 = x; f1 = x * x; f2 = u; f3 = 0.f; f4 = 0.f;
            } else {
                f0 = v; f1 = u * u; f2 = v * v; f3 = x * u; f4 = x * v;
            }
            #pragma unroll
            for (int s = 0; s < 16; ++s) {
                const float d = (seg == s + 1) ? 1.f : 0.f;
                if constexpr (GRP == 0) {
                    acc[0][s] += d;
                    acc[1][s] = fmaf(d, f0, acc[1][s]);
                    acc[2][s] = fmaf(d, f1, acc[2][s]);
                    acc[3][s] = fmaf(d, f2, acc[3][s]);
                } else {
                    acc[0][s] = fmaf(d, f0, acc[0][s]);
                    acc[1][s] = fmaf(d, f1, acc[1][s]);
                    acc[2][s] = fmaf(d, f2, acc[2][s]);
                    acc[3][s] = fmaf(d, f3, acc[3][s]);
                    acc[4][s] = fmaf(d, f4, acc[4][s]);
                }
            }
        }
        m4 = m4n; u4 = u4n; v4 = v4n;
    }

    // butterfly-reduce each accumulator across the wave
    #pragma unroll
    for (int k = 0; k < NK; ++k)
        #pragma unroll
        for (int s = 0; s < 16; ++s) {
            float t = acc[k][s];
            #pragma unroll
            for (int off = 32; off > 0; off >>= 1) t += __shfl_down(t, off);
            acc[k][s] = t;
        }

    if (lane == 0) {
        #pragma unroll 1
        for (int s = 0; s < 16; ++s) {
            double* c = cell + s * 14;
            if constexpr (GRP == 0) {
                const double N  = (double)acc[0][s];
                const double Sx = (double)acc[1][s];
                const double Sxx = (double)acc[2][s];
                const double Su = (double)acc[3][s];
                atomicAdd(c + 0, N);
                atomicAdd(c + 1, Sx);
                atomicAdd(c + 2, yd * N);
                atomicAdd(c + 3, Sxx);
                atomicAdd(c + 4, yd * Sx);
                atomicAdd(c + 5, yd * yd * N);
                atomicAdd(c + 6, Su);
                atomicAdd(c + 11, yd * Su);
            } else {
                const double Sv = (double)acc[0][s];
                atomicAdd(c + 7, Sv);
                atomicAdd(c + 8, (double)acc[1][s]);
                atomicAdd(c + 9, (double)acc[2][s]);
                atomicAdd(c + 10, (double)acc[3][s]);
                atomicAdd(c + 12, (double)acc[4][s]);
                atomicAdd(c + 13, yd * Sv);
            }
        }
    }
}

__global__ __launch_bounds__(256, 2) void moments_kernel(
    const float* __restrict__ flow,
    const int*   __restrict__ masks,
    double* __restrict__ moments4)    // [4][8*16*14]
{
    const int tid  = threadIdx.x;
    const int lane = tid & 63;
    const int wid  = tid >> 6;
    const long long base = (long long)blockIdx.x * 2048;  // 2 rows per block
    const int b   = (int)(base >> 19);
    const int h0  = (int)((base & (HW - 1)) >> 10);
    const int row = h0 + (wid & 1);
    const int par = blockIdx.x & 3;

    const float* fuR = flow + (long long)b * (2LL * HW) + row * WW;
    const float* fvR = fuR + HW;
    const int*   mkR = masks + (long long)b * HW + row * WW;
    double* cell = moments4 + par * 1792 + b * 224;

    if (wid < 2) mom_body<0>(fuR, fvR, mkR, lane, cell, (double)row);
    else         mom_body<1>(fuR, fvR, mkR, lane, cell, (double)row);
}

// ---------------- K_A: boundary, sobel, smooth (unchanged, validated) ----------------
__global__ __launch_bounds__(256) void stencil_kernel(
    const float* __restrict__ flow,
    const int*   __restrict__ masks,
    const float* __restrict__ images,
    double* __restrict__ scal64,      // [64][4]
    unsigned* __restrict__ maxfg64)   // [64]
{
    __shared__ float         sm[4][1032];
    __shared__ unsigned char smask[4][1032];
    __shared__ float         su[3][1024];
    __shared__ float         sv[3][1024];
    __shared__ float         sg[3][1024];
    __shared__ float         wred[4][5];

    const int tid = threadIdx.x;
    const int lane = tid & 63;
    const long long base = (long long)blockIdx.x * 2048;
    const int b  = (int)(base >> 19);
    const int h0 = (int)((base & (HW - 1)) >> 10);

    const float* fu = flow + (long long)b * (2LL * HW);
    const float* fv = fu + HW;
    const int*   mk = masks + (long long)b * HW;
    const float* i0 = images + (long long)b * (3LL * HW);
    const float* i1 = i0 + HW;
    const float* i2 = i1 + HW;

    const int c4 = tid * 4;
    #pragma unroll
    for (int r = 0; r < 4; ++r) {
        const int gr = h0 - 1 + r;
        const int mr = gr < 0 ? 0 : (gr > HH - 1 ? HH - 1 : gr);
        const int4 mv = *(const int4*)&mk[mr * WW + c4];
        uchar4 mb;
        mb.x = (unsigned char)mv.x; mb.y = (unsigned char)mv.y;
        mb.z = (unsigned char)mv.z; mb.w = (unsigned char)mv.w;
        *(uchar4*)&smask[r][4 + c4] = mb;

        float4 u4 = make_float4(0.f, 0.f, 0.f, 0.f);
        float4 v4 = make_float4(0.f, 0.f, 0.f, 0.f);
        if (gr >= 0 && gr <= HH - 1) {
            u4 = *(const float4*)&fu[gr * WW + c4];
            v4 = *(const float4*)&fv[gr * WW + c4];
        }
        float4 m4;
        m4.x = sqrtf(u4.x * u4.x + v4.x * v4.x);
        m4.y = sqrtf(u4.y * u4.y + v4.y * v4.y);
        m4.z = sqrtf(u4.z * u4.z + v4.z * v4.z);
        m4.w = sqrtf(u4.w * u4.w + v4.w * v4.w);
        *(float4*)&sm[r][4 + c4] = m4;
        if (r >= 1) {
            *(float4*)&su[r - 1][c4] = u4;
            *(float4*)&sv[r - 1][c4] = v4;
        }
    }
    #pragma unroll
    for (int r = 0; r < 3; ++r) {
        const int gr = h0 + r;
        float4 g4 = make_float4(0.f, 0.f, 0.f, 0.f);
        if (gr <= HH - 1) {
            const float4 a  = *(const float4*)&i0[gr * WW + c4];
            const float4 bq = *(const float4*)&i1[gr * WW + c4];
            const float4 c  = *(const float4*)&i2[gr * WW + c4];
            g4.x = (a.x + bq.x + c.x) * (1.f / 3.f);
            g4.y = (a.y + bq.y + c.y) * (1.f / 3.f);
            g4.z = (a.z + bq.z + c.z) * (1.f / 3.f);
            g4.w = (a.w + bq.w + c.w) * (1.f / 3.f);
        }
        *(float4*)&sg[r][c4] = g4;
    }
    if (tid < 4) {
        const int gr = h0 - 1 + tid;
        const int mr = gr < 0 ? 0 : (gr > HH - 1 ? HH - 1 : gr);
        smask[tid][3]    = (unsigned char)mk[mr * WW + 0];
        smask[tid][1028] = (unsigned char)mk[mr * WW + WW - 1];
        sm[tid][3] = 0.f;
        sm[tid][1028] = 0.f;
    }
    __syncthreads();

    float a_dx = 0.f, a_dy = 0.f, a_sb = 0.f, a_sbf = 0.f, mfg = 0.f;

    #pragma unroll
    for (int it = 0; it < 8; ++it) {
        const int idx = it * 256 + tid;
        const int lr = idx >> 10;
        const int w  = idx & 1023;
        const int h  = h0 + lr;
        const int cc = 4 + w;

        const int segc = smask[lr + 1][cc];
        int bnd = (smask[lr][cc - 1] != segc) | (smask[lr][cc] != segc) |
                  (smask[lr][cc + 1] != segc) |
                  (smask[lr + 1][cc - 1] != segc) | (smask[lr + 1][cc + 1] != segc) |
                  (smask[lr + 2][cc - 1] != segc) | (smask[lr + 2][cc] != segc) |
                  (smask[lr + 2][cc + 1] != segc);

        const float t00 = sm[lr][cc - 1],     t01 = sm[lr][cc],     t02 = sm[lr][cc + 1];
        const float t10 = sm[lr + 1][cc - 1],                       t12 = sm[lr + 1][cc + 1];
        const float t20 = sm[lr + 2][cc - 1], t21 = sm[lr + 2][cc], t22 = sm[lr + 2][cc + 1];
        const float fgx = (t02 - t00) + 2.f * (t12 - t10) + (t22 - t20);
        const float fgy = (t20 + 2.f * t21 + t22) - (t00 + 2.f * t01 + t02);
        const float fgraw = fabsf(fgx) + fabsf(fgy);
        mfg = fmaxf(mfg, fgraw);
        if (bnd) { a_sb += 1.f; a_sbf += fgraw; }

        const float u = su[lr][w], v = sv[lr][w];
        const float g0 = sg[lr][w];
        if (w < WW - 1) {
            const float wgt = expf(-fabsf(sg[lr][w + 1] - g0) * 10.f) * (bnd ? SUPPRESS : 1.f);
            a_dx += (fabsf(su[lr][w + 1] - u) + fabsf(sv[lr][w + 1] - v)) * wgt;
        }
        if (h < HH - 1) {
            const float wgt = expf(-fabsf(sg[lr + 1][w] - g0) * 10.f) * (bnd ? SUPPRESS : 1.f);
            a_dy += (fabsf(su[lr + 1][w] - u) + fabsf(sv[lr + 1][w] - v)) * wgt;
        }
    }

    for (int off = 32; off > 0; off >>= 1) {
        a_dx += __shfl_down(a_dx, off);
        a_dy += __shfl_down(a_dy, off);
        a_sb += __shfl_down(a_sb, off);
        a_sbf += __shfl_down(a_sbf, off);
        mfg = fmaxf(mfg, __shfl_down(mfg, off));
    }
    if (lane == 0) {
        const int wv = tid >> 6;
        wred[wv][0] = a_dx; wred[wv][1] = a_dy; wred[wv][2] = a_sb;
        wred[wv][3] = a_sbf; wred[wv][4] = mfg;
    }
    __syncthreads();
    if (tid == 0) {
        float dx = 0.f, dy = 0.f, sb = 0.f, sbf = 0.f, mf = 0.f;
        for (int i = 0; i < 4; ++i) {
            dx += wred[i][0]; dy += wred[i][1]; sb += wred[i][2];
            sbf += wred[i][3]; mf = fmaxf(mf, wred[i][4]);
        }
        const int sl = blockIdx.x & 63;
        atomicAdd(&scal64[sl * 4 + 0], (double)dx);
        atomicAdd(&scal64[sl * 4 + 1], (double)dy);
        atomicAdd(&scal64[sl * 4 + 2], (double)sb);
        atomicAdd(&scal64[sl * 4 + 3], (double)sbf);
        atomicMax(&maxfg64[sl], __float_as_uint(mf));
    }
}

// ---------------- solve: sum partials, 3x3 normal equations + variance ----------------
__global__ __launch_bounds__(128) void solve_kernel(
    const double* __restrict__ moments4,
    float* __restrict__ params,   // [128][6]
    int* __restrict__ valid,      // [128]
    float* __restrict__ out)
{
    const int i = threadIdx.x;    // (b, seg-1)
    double m[14];
    #pragma unroll
    for (int k = 0; k < 14; ++k) {
        double s = 0.0;
        #pragma unroll
        for (int par = 0; par < 4; ++par) s += moments4[par * 1792 + i * 14 + k];
        m[k] = s;
    }
    const double n = m[0];
    const int vh = (n >= 100.0) ? 1 : 0;
    float p[6] = {0.f, 0.f, 0.f, 0.f, 0.f, 0.f};
    if (vh) {
        double A[3][3] = {{m[3], m[4], m[1]},
                          {m[4], m[5], m[2]},
                          {m[1], m[2], n}};
        double Bm[3][2] = {{m[10], m[12]},
                           {m[11], m[13]},
                           {m[6],  m[7]}};
        for (int k = 0; k < 3; ++k) {
            int piv = k; double mx = fabs(A[k][k]);
            for (int r = k + 1; r < 3; ++r) {
                double a = fabs(A[r][k]);
                if (a > mx) { mx = a; piv = r; }
            }
            if (piv != k) {
                for (int c = 0; c < 3; ++c) { double t = A[k][c]; A[k][c] = A[piv][c]; A[piv][c] = t; }
                for (int c = 0; c < 2; ++c) { double t = Bm[k][c]; Bm[k][c] = Bm[piv][c]; Bm[piv][c] = t; }
            }
            const double inv = 1.0 / A[k][k];
            for (int r = k + 1; r < 3; ++r) {
                const double f = A[r][k] * inv;
                for (int c = k; c < 3; ++c) A[r][c] -= f * A[k][c];
                Bm[r][0] -= f * Bm[k][0];
                Bm[r][1] -= f * Bm[k][1];
            }
        }
        double X[3][2];
        for (int c = 0; c < 2; ++c) {
            X[2][c] = Bm[2][c] / A[2][2];
            X[1][c] = (Bm[1][c] - A[1][2] * X[2][c]) / A[1][1];
            X[0][c] = (Bm[0][c] - A[0][1] * X[1][c] - A[0][2] * X[2][c]) / A[0][0];
        }
        p[0] = (float)X[0][0]; p[1] = (float)X[1][0]; p[2] = (float)X[2][0];
        p[3] = (float)X[0][1]; p[4] = (float)X[1][1]; p[5] = (float)X[2][1];
    }
    valid[i] = vh;
    for (int c = 0; c < 6; ++c) params[i * 6 + c] = p[c];

    const int vv = (n >= 50.0) ? 1 : 0;
    double var = 0.0;
    if (vv) {
        const double ns = (n > 2.0) ? n : 2.0;
        const double var_u = (m[8] - m[6] * m[6] / ns) / (ns - 1.0);
        const double var_v = (m[9] - m[7] * m[7] / ns) / (ns - 1.0);
        var = var_u + var_v;
    }
    __shared__ double svar[128];
    __shared__ int scnt[128];
    svar[i] = var; scnt[i] = vv;
    __syncthreads();
    for (int s = 64; s > 0; s >>= 1) {
        if (i < s) { svar[i] += svar[i + s]; scnt[i] += scnt[i + s]; }
        __syncthreads();
    }
    if (i == 0) out[2] = (float)(svar[0] / (double)(scnt[0] > 1 ? scnt[0] : 1));
}

// ---------------- pass 2: residuals via delta-predicated register accumulation ----------------
__global__ __launch_bounds__(256, 4) void pass2_kernel(
    const float* __restrict__ flow,
    const int*   __restrict__ masks,
    const float* __restrict__ params,
    double* __restrict__ res4)        // [4][8][16]
{
    __shared__ float sp[17 * 6];      // row 0 = zeros (background)

    const long long base = (long long)blockIdx.x * 4096;
    const int b      = (int)(base >> 19);
    const int hwbase = (int)(base & (HW - 1));
    const int tid    = threadIdx.x;
    const int lane   = tid & 63;

    if (tid < 6) sp[tid] = 0.f;
    if (tid < 96) sp[6 + tid] = params[b * 96 + tid];
    __syncthreads();

    const float* fu = flow + (long long)b * (2LL * HW);
    const float* fv = fu + HW;
    const int*   mk = masks + (long long)b * HW;

    float acc[16];
    #pragma unroll
    for (int s = 0; s < 16; ++s) acc[s] = 0.f;

    #pragma unroll 1
    for (int it = 0; it < 4; ++it) {
        const int i4 = hwbase + it * 1024 + tid * 4;
        const int4   m4 = *(const int4*)&mk[i4];
        const float4 u4 = *(const float4*)&fu[i4];
        const float4 v4 = *(const float4*)&fv[i4];
        const int segs[4] = {m4.x, m4.y, m4.z, m4.w};
        const float us[4] = {u4.x, u4.y, u4.z, u4.w};
        const float vs[4] = {v4.x, v4.y, v4.z, v4.w};
        #pragma unroll
        for (int j = 0; j < 4; ++j) {
            const int seg = segs[j];
            const float* pf = &sp[seg * 6];
            const int hw = i4 + j;
            const float x = (float)(hw & 1023), y = (float)((hw & (HW - 1)) >> 10);
            const float du = us[j] - (x * pf[0] + y * pf[1] + pf[2]);
            const float dv = vs[j] - (x * pf[3] + y * pf[4] + pf[5]);
            const float r = sqrtf(du * du + dv * dv);
            #pragma unroll
            for (int s = 0; s < 16; ++s)
                acc[s] += (seg == s + 1) ? r : 0.f;
        }
    }

    const int par = blockIdx.x & 3;
    #pragma unroll
    for (int s = 0; s < 16; ++s) {
        float vsum = acc[s];
        #pragma unroll
        for (int off = 32; off > 0; off >>= 1) vsum += __shfl_down(vsum, off);
        if (lane == 0)
            atomicAdd(&res4[par * 128 + b * 16 + s], (double)vsum);
    }
}

// ---------------- finalize: homog, sharp, smooth ----------------
__global__ __launch_bounds__(128) void final_kernel(
    const double* __restrict__ moments4,
    const double* __restrict__ res4,
    const int*    __restrict__ valid,
    const double* __restrict__ scal64,
    const unsigned* __restrict__ maxfg64,
    float* __restrict__ out)
{
    const int i = threadIdx.x;
    double n = 0.0, rs = 0.0;
    #pragma unroll
    for (int par = 0; par < 4; ++par) {
        n  += moments4[par * 1792 + i * 14];
        rs += res4[par * 128 + i];
    }
    const int vh = valid[i];
    const double rm = vh ? rs / (n > 1.0 ? n : 1.0) : 0.0;
    __shared__ double sr[128];
    __shared__ int sc[128];
    sr[i] = rm; sc[i] = vh;
    __syncthreads();
    for (int s = 64; s > 0; s >>= 1) {
        if (i < s) { sr[i] += sr[i + s]; sc[i] += sc[i + s]; }
        __syncthreads();
    }
    if (i == 0) {
        out[0] = (float)(sr[0] / (double)(sc[0] > 1 ? sc[0] : 1));
        double dx = 0.0, dy = 0.0, sb = 0.0, sbf = 0.0;
        float mf = 0.f;
        for (int k = 0; k < 64; ++k) {
            dx += scal64[k * 4 + 0]; dy += scal64[k * 4 + 1];
            sb += scal64[k * 4 + 2]; sbf += scal64[k * 4 + 3];
            mf = fmaxf(mf, __uint_as_float(maxfg64[k]));
        }
        const double maxfg = (double)mf;
        const double maxb = (sb > 0.0) ? 1.0 : 0.0;
        out[1] = (float)((sb - sbf / (maxfg + 1e-6)) / (maxb + 1e-6) / (double)NPIX);
        const double smooth = dx / (double)(2LL * BB * HH * (WW - 1)) +
                              dy / (double)(2LL * BB * (HH - 1) * WW);
        out[3] = (float)smooth;
    }
}

extern "C" void kernel_launch(void* const* d_in, const int* in_sizes, int n_in,
                              void* d_out, int out_size, void* d_ws, size_t ws_size,
                              hipStream_t stream)
{
    const float* flow   = (const float*)d_in[0];
    const int*   masks  = (const int*)d_in[1];
    const float* images = (const float*)d_in[2];
    float* out = (float*)d_out;

    char* ws = (char*)d_ws;
    double*   moments4 = (double*)(ws);             // 0     .. 57344
    double*   res4     = (double*)(ws + 57344);     // 57344 .. 61440
    double*   scal64   = (double*)(ws + 61440);     // 61440 .. 63488
    unsigned* maxfg64  = (unsigned*)(ws + 63488);   // 63488 .. 63744
    float*    params   = (float*)(ws + 63744);      // 63744 .. 66816
    int*      valid    = (int*)(ws + 66816);        // 66816 .. 67328

    hipMemsetAsync(d_ws, 0, 67584, stream);

    moments_kernel<<<dim3(NPIX / 2048), dim3(256), 0, stream>>>(flow, masks, moments4);
    stencil_kernel<<<dim3(NPIX / 2048), dim3(256), 0, stream>>>(
        flow, masks, images, scal64, maxfg64);
    solve_kernel<<<dim3(1), dim3(128), 0, stream>>>(moments4, params, valid, out);
    pass2_kernel<<<dim3(NPIX / 4096), dim3(256), 0, stream>>>(
        flow, masks, params, res4);
    final_kernel<<<dim3(1), dim3(128), 0, stream>>>(
        moments4, res4, valid, scal64, maxfg64, out);
}

// Round 7
// 242.104 us; speedup vs baseline: 1.3675x; 1.3675x over previous
//
#include <hip/hip_runtime.h>
#include <math.h>

#define BB 8
#define HH 512
#define WW 1024
#define HW (HH * WW)          // 524288 = 2^19
#define NPIX (BB * HW)        // 4194304
#define NSEG 16               // segments 1..16 (0 skipped)
#define SUPPRESS 0.1f

// ws layout (bytes):
//   moments4 : double[4][8][16][14] @ 0      (57344)   4-way spread partials
//   res4     : double[4][8][16]     @ 57344  (4096)
//   scal64   : double[64][4]        @ 61440  (2048)    [dx,dy,Sb,Sbf] partials
//   maxfg64  : unsigned[64]         @ 63488  (256)
//   params   : float[128*6]         @ 63744  (3072)
//   valid    : int[128]             @ 66816  (512)

__device__ __forceinline__ float wave_sum(float t) {
    #pragma unroll
    for (int off = 32; off > 0; off >>= 1) t += __shfl_down(t, off);
    return t;
}

// ---------------- K_M: segment moments, named-scalar accumulators ----------------
// r6 lesson (rule #20): ANY runtime-indexed local array -> scratch (225 MB spill
// writes, VGPR=64). Here accumulators are macro-generated named scalars; per wave
// <=40 floats. Block=512thr (8 waves) = (row:2) x (featgrp:2) x (seghalf:2).
// Feature groups: GRP0 {N,Sx,Sxx,Su}, GRP1 {Sv,Suu,Svv,Sxu,Sxv}.
// y-moments derived at flush: Sy=yN, Sxy=ySx, Syy=y^2N, Syu=ySu, Syv=ySv.
// moment order: [n,Sx,Sy,Sxx,Sxy,Syy,Su,Sv,Suu,Svv,Sxu,Syu,Sxv,Syv]
#define REP8(M) M(0) M(1) M(2) M(3) M(4) M(5) M(6) M(7)

__device__ __forceinline__ void mom_grp0(
    const float* __restrict__ fuR, const int* __restrict__ mkR,
    int lane, int segbase, double* __restrict__ cell, double yd)
{
#define DECL0(i) float n_##i = 0.f, sx_##i = 0.f, sxx_##i = 0.f, su_##i = 0.f;
    REP8(DECL0)
    const int sb1 = segbase + 1;
    #pragma unroll
    for (int it = 0; it < 4; ++it) {
        const int o = it * 256 + lane * 4;
        const int4   m4 = *(const int4*)&mkR[o];
        const float4 u4 = *(const float4*)&fuR[o];
        const int   segs[4] = {m4.x, m4.y, m4.z, m4.w};
        const float us[4]   = {u4.x, u4.y, u4.z, u4.w};
        #pragma unroll
        for (int j = 0; j < 4; ++j) {
            const int   sr = segs[j] - sb1;
            const float x  = (float)(o + j);
            const float xx = x * x;
            const float u  = us[j];
#define STEP0(i) { const float d = (sr == i) ? 1.f : 0.f; \
            n_##i += d; sx_##i = fmaf(d, x, sx_##i); \
            sxx_##i = fmaf(d, xx, sxx_##i); su_##i = fmaf(d, u, su_##i); }
            REP8(STEP0)
        }
    }
#define FIN0(i) { \
    const float N = wave_sum(n_##i), SX = wave_sum(sx_##i); \
    const float SXX = wave_sum(sxx_##i), SU = wave_sum(su_##i); \
    if (lane == 0) { \
        double* c = cell + (segbase + i) * 14; \
        atomicAdd(c + 0, (double)N); \
        atomicAdd(c + 1, (double)SX); \
        atomicAdd(c + 2, yd * (double)N); \
        atomicAdd(c + 3, (double)SXX); \
        atomicAdd(c + 4, yd * (double)SX); \
        atomicAdd(c + 5, yd * yd * (double)N); \
        atomicAdd(c + 6, (double)SU); \
        atomicAdd(c + 11, yd * (double)SU); } }
    REP8(FIN0)
}

__device__ __forceinline__ void mom_grp1(
    const float* __restrict__ fuR, const float* __restrict__ fvR,
    const int* __restrict__ mkR,
    int lane, int segbase, double* __restrict__ cell, double yd)
{
#define DECL1(i) float sv_##i = 0.f, suu_##i = 0.f, svv_##i = 0.f, \
                       sxu_##i = 0.f, sxv_##i = 0.f;
    REP8(DECL1)
    const int sb1 = segbase + 1;
    #pragma unroll
    for (int it = 0; it < 4; ++it) {
        const int o = it * 256 + lane * 4;
        const int4   m4 = *(const int4*)&mkR[o];
        const float4 u4 = *(const float4*)&fuR[o];
        const float4 v4 = *(const float4*)&fvR[o];
        const int   segs[4] = {m4.x, m4.y, m4.z, m4.w};
        const float us[4]   = {u4.x, u4.y, u4.z, u4.w};
        const float vs[4]   = {v4.x, v4.y, v4.z, v4.w};
        #pragma unroll
        for (int j = 0; j < 4; ++j) {
            const int   sr = segs[j] - sb1;
            const float x  = (float)(o + j);
            const float u  = us[j], v = vs[j];
            const float uu = u * u, vv = v * v, xu = x * u, xv = x * v;
#define STEP1(i) { const float d = (sr == i) ? 1.f : 0.f; \
            sv_##i = fmaf(d, v, sv_##i); suu_##i = fmaf(d, uu, suu_##i); \
            svv_##i = fmaf(d, vv, svv_##i); sxu_##i = fmaf(d, xu, sxu_##i); \
            sxv_##i = fmaf(d, xv, sxv_##i); }
            REP8(STEP1)
        }
    }
#define FIN1(i) { \
    const float SV = wave_sum(sv_##i), SUU = wave_sum(suu_##i); \
    const float SVV = wave_sum(svv_##i), SXU = wave_sum(sxu_##i); \
    const float SXV = wave_sum(sxv_##i); \
    if (lane == 0) { \
        double* c = cell + (segbase + i) * 14; \
        atomicAdd(c + 7, (double)SV); \
        atomicAdd(c + 8, (double)SUU); \
        atomicAdd(c + 9, (double)SVV); \
        atomicAdd(c + 10, (double)SXU); \
        atomicAdd(c + 12, (double)SXV); \
        atomicAdd(c + 13, yd * (double)SV); } }
    REP8(FIN1)
}

__global__ __launch_bounds__(512) void moments_kernel(
    const float* __restrict__ flow,
    const int*   __restrict__ masks,
    double* __restrict__ moments4)    // [4][8*16*14]
{
    const int tid  = threadIdx.x;
    const int lane = tid & 63;
    const int wid  = tid >> 6;             // 0..7
    const int rowo = wid & 1;
    const int grp  = (wid >> 1) & 1;
    const int segbase = ((wid >> 2) & 1) * 8;

    const long long base = (long long)blockIdx.x * 2048;  // 2 rows per block
    const int b   = (int)(base >> 19);
    const int h0  = (int)((base & (HW - 1)) >> 10);
    const int row = h0 + rowo;
    const int par = blockIdx.x & 3;

    const float* fuR = flow + (long long)b * (2LL * HW) + row * WW;
    const float* fvR = fuR + HW;
    const int*   mkR = masks + (long long)b * HW + row * WW;
    double* cell = moments4 + par * 1792 + b * 224;
    const double yd = (double)row;

    if (grp == 0) mom_grp0(fuR, mkR, lane, segbase, cell, yd);
    else          mom_grp1(fuR, fvR, mkR, lane, segbase, cell, yd);
}

// ---------------- K_A: boundary, sobel, smooth (unchanged, validated) ----------------
__global__ __launch_bounds__(256) void stencil_kernel(
    const float* __restrict__ flow,
    const int*   __restrict__ masks,
    const float* __restrict__ images,
    double* __restrict__ scal64,      // [64][4]
    unsigned* __restrict__ maxfg64)   // [64]
{
    __shared__ float         sm[4][1032];
    __shared__ unsigned char smask[4][1032];
    __shared__ float         su[3][1024];
    __shared__ float         sv[3][1024];
    __shared__ float         sg[3][1024];
    __shared__ float         wred[4][5];

    const int tid = threadIdx.x;
    const int lane = tid & 63;
    const long long base = (long long)blockIdx.x * 2048;
    const int b  = (int)(base >> 19);
    const int h0 = (int)((base & (HW - 1)) >> 10);

    const float* fu = flow + (long long)b * (2LL * HW);
    const float* fv = fu + HW;
    const int*   mk = masks + (long long)b * HW;
    const float* i0 = images + (long long)b * (3LL * HW);
    const float* i1 = i0 + HW;
    const float* i2 = i1 + HW;

    const int c4 = tid * 4;
    #pragma unroll
    for (int r = 0; r < 4; ++r) {
        const int gr = h0 - 1 + r;
        const int mr = gr < 0 ? 0 : (gr > HH - 1 ? HH - 1 : gr);
        const int4 mv = *(const int4*)&mk[mr * WW + c4];
        uchar4 mb;
        mb.x = (unsigned char)mv.x; mb.y = (unsigned char)mv.y;
        mb.z = (unsigned char)mv.z; mb.w = (unsigned char)mv.w;
        *(uchar4*)&smask[r][4 + c4] = mb;

        float4 u4 = make_float4(0.f, 0.f, 0.f, 0.f);
        float4 v4 = make_float4(0.f, 0.f, 0.f, 0.f);
        if (gr >= 0 && gr <= HH - 1) {
            u4 = *(const float4*)&fu[gr * WW + c4];
            v4 = *(const float4*)&fv[gr * WW + c4];
        }
        float4 m4;
        m4.x = sqrtf(u4.x * u4.x + v4.x * v4.x);
        m4.y = sqrtf(u4.y * u4.y + v4.y * v4.y);
        m4.z = sqrtf(u4.z * u4.z + v4.z * v4.z);
        m4.w = sqrtf(u4.w * u4.w + v4.w * v4.w);
        *(float4*)&sm[r][4 + c4] = m4;
        if (r >= 1) {
            *(float4*)&su[r - 1][c4] = u4;
            *(float4*)&sv[r - 1][c4] = v4;
        }
    }
    #pragma unroll
    for (int r = 0; r < 3; ++r) {
        const int gr = h0 + r;
        float4 g4 = make_float4(0.f, 0.f, 0.f, 0.f);
        if (gr <= HH - 1) {
            const float4 a  = *(const float4*)&i0[gr * WW + c4];
            const float4 bq = *(const float4*)&i1[gr * WW + c4];
            const float4 c  = *(const float4*)&i2[gr * WW + c4];
            g4.x = (a.x + bq.x + c.x) * (1.f / 3.f);
            g4.y = (a.y + bq.y + c.y) * (1.f / 3.f);
            g4.z = (a.z + bq.z + c.z) * (1.f / 3.f);
            g4.w = (a.w + bq.w + c.w) * (1.f / 3.f);
        }
        *(float4*)&sg[r][c4] = g4;
    }
    if (tid < 4) {
        const int gr = h0 - 1 + tid;
        const int mr = gr < 0 ? 0 : (gr > HH - 1 ? HH - 1 : gr);
        smask[tid][3]    = (unsigned char)mk[mr * WW + 0];
        smask[tid][1028] = (unsigned char)mk[mr * WW + WW - 1];
        sm[tid][3] = 0.f;
        sm[tid][1028] = 0.f;
    }
    __syncthreads();

    float a_dx = 0.f, a_dy = 0.f, a_sb = 0.f, a_sbf = 0.f, mfg = 0.f;

    #pragma unroll
    for (int it = 0; it < 8; ++it) {
        const int idx = it * 256 + tid;
        const int lr = idx >> 10;
        const int w  = idx & 1023;
        const int h  = h0 + lr;
        const int cc = 4 + w;

        const int segc = smask[lr + 1][cc];
        int bnd = (smask[lr][cc - 1] != segc) | (smask[lr][cc] != segc) |
                  (smask[lr][cc + 1] != segc) |
                  (smask[lr + 1][cc - 1] != segc) | (smask[lr + 1][cc + 1] != segc) |
                  (smask[lr + 2][cc - 1] != segc) | (smask[lr + 2][cc] != segc) |
                  (smask[lr + 2][cc + 1] != segc);

        const float t00 = sm[lr][cc - 1],     t01 = sm[lr][cc],     t02 = sm[lr][cc + 1];
        const float t10 = sm[lr + 1][cc - 1],                       t12 = sm[lr + 1][cc + 1];
        const float t20 = sm[lr + 2][cc - 1], t21 = sm[lr + 2][cc], t22 = sm[lr + 2][cc + 1];
        const float fgx = (t02 - t00) + 2.f * (t12 - t10) + (t22 - t20);
        const float fgy = (t20 + 2.f * t21 + t22) - (t00 + 2.f * t01 + t02);
        const float fgraw = fabsf(fgx) + fabsf(fgy);
        mfg = fmaxf(mfg, fgraw);
        if (bnd) { a_sb += 1.f; a_sbf += fgraw; }

        const float u = su[lr][w], v = sv[lr][w];
        const float g0 = sg[lr][w];
        if (w < WW - 1) {
            const float wgt = expf(-fabsf(sg[lr][w + 1] - g0) * 10.f) * (bnd ? SUPPRESS : 1.f);
            a_dx += (fabsf(su[lr][w + 1] - u) + fabsf(sv[lr][w + 1] - v)) * wgt;
        }
        if (h < HH - 1) {
            const float wgt = expf(-fabsf(sg[lr + 1][w] - g0) * 10.f) * (bnd ? SUPPRESS : 1.f);
            a_dy += (fabsf(su[lr + 1][w] - u) + fabsf(sv[lr + 1][w] - v)) * wgt;
        }
    }

    for (int off = 32; off > 0; off >>= 1) {
        a_dx += __shfl_down(a_dx, off);
        a_dy += __shfl_down(a_dy, off);
        a_sb += __shfl_down(a_sb, off);
        a_sbf += __shfl_down(a_sbf, off);
        mfg = fmaxf(mfg, __shfl_down(mfg, off));
    }
    if (lane == 0) {
        const int wv = tid >> 6;
        wred[wv][0] = a_dx; wred[wv][1] = a_dy; wred[wv][2] = a_sb;
        wred[wv][3] = a_sbf; wred[wv][4] = mfg;
    }
    __syncthreads();
    if (tid == 0) {
        float dx = 0.f, dy = 0.f, sb = 0.f, sbf = 0.f, mf = 0.f;
        for (int i = 0; i < 4; ++i) {
            dx += wred[i][0]; dy += wred[i][1]; sb += wred[i][2];
            sbf += wred[i][3]; mf = fmaxf(mf, wred[i][4]);
        }
        const int sl = blockIdx.x & 63;
        atomicAdd(&scal64[sl * 4 + 0], (double)dx);
        atomicAdd(&scal64[sl * 4 + 1], (double)dy);
        atomicAdd(&scal64[sl * 4 + 2], (double)sb);
        atomicAdd(&scal64[sl * 4 + 3], (double)sbf);
        atomicMax(&maxfg64[sl], __float_as_uint(mf));
    }
}

// ---------------- solve: sum partials, 3x3 normal equations + variance ----------------
__global__ __launch_bounds__(128) void solve_kernel(
    const double* __restrict__ moments4,
    float* __restrict__ params,   // [128][6]
    int* __restrict__ valid,      // [128]
    float* __restrict__ out)
{
    const int i = threadIdx.x;    // (b, seg-1)
    double m[14];
    #pragma unroll
    for (int k = 0; k < 14; ++k) {
        double s = 0.0;
        #pragma unroll
        for (int par = 0; par < 4; ++par) s += moments4[par * 1792 + i * 14 + k];
        m[k] = s;
    }
    const double n = m[0];
    const int vh = (n >= 100.0) ? 1 : 0;
    float p[6] = {0.f, 0.f, 0.f, 0.f, 0.f, 0.f};
    if (vh) {
        double A[3][3] = {{m[3], m[4], m[1]},
                          {m[4], m[5], m[2]},
                          {m[1], m[2], n}};
        double Bm[3][2] = {{m[10], m[12]},
                           {m[11], m[13]},
                           {m[6],  m[7]}};
        for (int k = 0; k < 3; ++k) {
            int piv = k; double mx = fabs(A[k][k]);
            for (int r = k + 1; r < 3; ++r) {
                double a = fabs(A[r][k]);
                if (a > mx) { mx = a; piv = r; }
            }
            if (piv != k) {
                for (int c = 0; c < 3; ++c) { double t = A[k][c]; A[k][c] = A[piv][c]; A[piv][c] = t; }
                for (int c = 0; c < 2; ++c) { double t = Bm[k][c]; Bm[k][c] = Bm[piv][c]; Bm[piv][c] = t; }
            }
            const double inv = 1.0 / A[k][k];
            for (int r = k + 1; r < 3; ++r) {
                const double f = A[r][k] * inv;
                for (int c = k; c < 3; ++c) A[r][c] -= f * A[k][c];
                Bm[r][0] -= f * Bm[k][0];
                Bm[r][1] -= f * Bm[k][1];
            }
        }
        double X[3][2];
        for (int c = 0; c < 2; ++c) {
            X[2][c] = Bm[2][c] / A[2][2];
            X[1][c] = (Bm[1][c] - A[1][2] * X[2][c]) / A[1][1];
            X[0][c] = (Bm[0][c] - A[0][1] * X[1][c] - A[0][2] * X[2][c]) / A[0][0];
        }
        p[0] = (float)X[0][0]; p[1] = (float)X[1][0]; p[2] = (float)X[2][0];
        p[3] = (float)X[0][1]; p[4] = (float)X[1][1]; p[5] = (float)X[2][1];
    }
    valid[i] = vh;
    for (int c = 0; c < 6; ++c) params[i * 6 + c] = p[c];

    const int vv = (n >= 50.0) ? 1 : 0;
    double var = 0.0;
    if (vv) {
        const double ns = (n > 2.0) ? n : 2.0;
        const double var_u = (m[8] - m[6] * m[6] / ns) / (ns - 1.0);
        const double var_v = (m[9] - m[7] * m[7] / ns) / (ns - 1.0);
        var = var_u + var_v;
    }
    __shared__ double svar[128];
    __shared__ int scnt[128];
    svar[i] = var; scnt[i] = vv;
    __syncthreads();
    for (int s = 64; s > 0; s >>= 1) {
        if (i < s) { svar[i] += svar[i + s]; scnt[i] += scnt[i + s]; }
        __syncthreads();
    }
    if (i == 0) out[2] = (float)(svar[0] / (double)(scnt[0] > 1 ? scnt[0] : 1));
}

// ---------------- pass 2: residuals, named-scalar accumulators ----------------
__global__ __launch_bounds__(256) void pass2_kernel(
    const float* __restrict__ flow,
    const int*   __restrict__ masks,
    const float* __restrict__ params,
    double* __restrict__ res4)        // [4][8][16]
{
    __shared__ float sp[17 * 6];      // row 0 = zeros (background)

    const long long base = (long long)blockIdx.x * 4096;
    const int b      = (int)(base >> 19);
    const int hwbase = (int)(base & (HW - 1));
    const int tid    = threadIdx.x;
    const int lane   = tid & 63;

    if (tid < 6) sp[tid] = 0.f;
    if (tid < 96) sp[6 + tid] = params[b * 96 + tid];
    __syncthreads();

    const float* fu = flow + (long long)b * (2LL * HW);
    const float* fv = fu + HW;
    const int*   mk = masks + (long long)b * HW;

#define DECLR(i) float r_##i = 0.f;
    REP8(DECLR)
#define DECLR2(i) float q_##i = 0.f;
    REP8(DECLR2)

    #pragma unroll
    for (int it = 0; it < 4; ++it) {
        const int i4 = hwbase + it * 1024 + tid * 4;
        const int4   m4 = *(const int4*)&mk[i4];
        const float4 u4 = *(const float4*)&fu[i4];
        const float4 v4 = *(const float4*)&fv[i4];
        const int segs[4] = {m4.x, m4.y, m4.z, m4.w};
        const float us[4] = {u4.x, u4.y, u4.z, u4.w};
        const float vs[4] = {v4.x, v4.y, v4.z, v4.w};
        #pragma unroll
        for (int j = 0; j < 4; ++j) {
            const int seg = segs[j];
            const float* pf = &sp[seg * 6];
            const int hw = i4 + j;
            const float x = (float)(hw & 1023), y = (float)((hw & (HW - 1)) >> 10);
            const float du = us[j] - (x * pf[0] + y * pf[1] + pf[2]);
            const float dv = vs[j] - (x * pf[3] + y * pf[4] + pf[5]);
            const float r = sqrtf(du * du + dv * dv);
            const int sr = seg - 1;
#define STEPR(i) r_##i += (sr == i) ? r : 0.f;
            REP8(STEPR)
#define STEPR2(i) q_##i += (sr == 8 + i) ? r : 0.f;
            REP8(STEPR2)
        }
    }

    const int par = blockIdx.x & 3;
    double* rb = &res4[par * 128 + b * 16];
#define FINR(i) { const float s = wave_sum(r_##i); \
    if (lane == 0) atomicAdd(rb + i, (double)s); }
    REP8(FINR)
#define FINR2(i) { const float s = wave_sum(q_##i); \
    if (lane == 0) atomicAdd(rb + 8 + i, (double)s); }
    REP8(FINR2)
}

// ---------------- finalize: homog, sharp, smooth ----------------
__global__ __launch_bounds__(128) void final_kernel(
    const double* __restrict__ moments4,
    const double* __restrict__ res4,
    const int*    __restrict__ valid,
    const double* __restrict__ scal64,
    const unsigned* __restrict__ maxfg64,
    float* __restrict__ out)
{
    const int i = threadIdx.x;
    double n = 0.0, rs = 0.0;
    #pragma unroll
    for (int par = 0; par < 4; ++par) {
        n  += moments4[par * 1792 + i * 14];
        rs += res4[par * 128 + i];
    }
    const int vh = valid[i];
    const double rm = vh ? rs / (n > 1.0 ? n : 1.0) : 0.0;
    __shared__ double sr[128];
    __shared__ int sc[128];
    sr[i] = rm; sc[i] = vh;
    __syncthreads();
    for (int s = 64; s > 0; s >>= 1) {
        if (i < s) { sr[i] += sr[i + s]; sc[i] += sc[i + s]; }
        __syncthreads();
    }
    if (i == 0) {
        out[0] = (float)(sr[0] / (double)(sc[0] > 1 ? sc[0] : 1));
        double dx = 0.0, dy = 0.0, sb = 0.0, sbf = 0.0;
        float mf = 0.f;
        for (int k = 0; k < 64; ++k) {
            dx += scal64[k * 4 + 0]; dy += scal64[k * 4 + 1];
            sb += scal64[k * 4 + 2]; sbf += scal64[k * 4 + 3];
            mf = fmaxf(mf, __uint_as_float(maxfg64[k]));
        }
        const double maxfg = (double)mf;
        const double maxb = (sb > 0.0) ? 1.0 : 0.0;
        out[1] = (float)((sb - sbf / (maxfg + 1e-6)) / (maxb + 1e-6) / (double)NPIX);
        const double smooth = dx / (double)(2LL * BB * HH * (WW - 1)) +
                              dy / (double)(2LL * BB * (HH - 1) * WW);
        out[3] = (float)smooth;
    }
}

extern "C" void kernel_launch(void* const* d_in, const int* in_sizes, int n_in,
                              void* d_out, int out_size, void* d_ws, size_t ws_size,
                              hipStream_t stream)
{
    const float* flow   = (const float*)d_in[0];
    const int*   masks  = (const int*)d_in[1];
    const float* images = (const float*)d_in[2];
    float* out = (float*)d_out;

    char* ws = (char*)d_ws;
    double*   moments4 = (double*)(ws);             // 0     .. 57344
    double*   res4     = (double*)(ws + 57344);     // 57344 .. 61440
    double*   scal64   = (double*)(ws + 61440);     // 61440 .. 63488
    unsigned* maxfg64  = (unsigned*)(ws + 63488);   // 63488 .. 63744
    float*    params   = (float*)(ws + 63744);      // 63744 .. 66816
    int*      valid    = (int*)(ws + 66816);        // 66816 .. 67328

    hipMemsetAsync(d_ws, 0, 67584, stream);

    moments_kernel<<<dim3(NPIX / 2048), dim3(512), 0, stream>>>(flow, masks, moments4);
    stencil_kernel<<<dim3(NPIX / 2048), dim3(256), 0, stream>>>(
        flow, masks, images, scal64, maxfg64);
    solve_kernel<<<dim3(1), dim3(128), 0, stream>>>(moments4, params, valid, out);
    pass2_kernel<<<dim3(NPIX / 4096), dim3(256), 0, stream>>>(
        flow, masks, params, res4);
    final_kernel<<<dim3(1), dim3(128), 0, stream>>>(
        moments4, res4, valid, scal64, maxfg64, out);
}